// Round 6
// baseline (124.541 us; speedup 1.0000x reference)
//
#include <hip/hip_runtime.h>
#include <math.h>

// Problem constants
#define H_   768
#define NH_  12
#define DH_  64
#define NL_  50
#define NCH_ 32      // number of 256-key subchunks
#define SC_  256     // keys per subchunk
#define NC_  16
#define S_   8192
#define NT_  24      // K-steps (768/32)

typedef __attribute__((ext_vector_type(8))) short short8;
typedef __attribute__((ext_vector_type(4))) float f32x4;
typedef unsigned short u16;

#define AS1(p) ((const __attribute__((address_space(1))) void*)(p))
#define AS3(p) ((__attribute__((address_space(3))) void*)(p))

__device__ inline u16 f2b(float f) {
    union { float f; unsigned u; } x; x.f = f;
    return (u16)((x.u + 0x7FFFu + ((x.u >> 16) & 1u)) >> 16);
}

// ---------------------------------------------------------------------------
// prep_all: convert fp32 inputs to bf16 laid out in EXACT MFMA fragment order:
//   frag granule (rt, kt, lane) holds  X[rt*16 + (lane&15)][kt*32 + (lane>>4)*8 .. +8]
//   flat elem offset = ((rt*24 + kt)*64 + lane)*8
// Sections (blocks): enc->afrag 3072 | ipw->bfragQ/bfragKV 864 |
//                    lq->afragLQ 48 | lw->afragLW 48 | ow->bfragM2 288
// ---------------------------------------------------------------------------
__global__ __launch_bounds__(256)
void prep_all(const float* __restrict__ enc, const float* __restrict__ ipw,
              const float* __restrict__ lq, const float* __restrict__ lwt,
              const float* __restrict__ ow,
              u16* __restrict__ afrag, u16* __restrict__ bfragKV,
              u16* __restrict__ bfragQ, u16* __restrict__ afragLQ,
              u16* __restrict__ afragLW, u16* __restrict__ bfragM2)
{
    int b = blockIdx.x;
    const int t = threadIdx.x;
    if (b < 3072) {            // enc (8192x768) -> afrag, input-linear
        const int u  = b * 256 + t;        // 8-elem granule
        const int i8 = u * 8;
        const int m = i8 / H_, kc8 = (i8 % H_) / 8;
        const float4 v0 = *reinterpret_cast<const float4*>(enc + i8);
        const float4 v1 = *reinterpret_cast<const float4*>(enc + i8 + 4);
        short8 o;
        o[0]=f2b(v0.x); o[1]=f2b(v0.y); o[2]=f2b(v0.z); o[3]=f2b(v0.w);
        o[4]=f2b(v1.x); o[5]=f2b(v1.y); o[6]=f2b(v1.z); o[7]=f2b(v1.w);
        const long go = ((long)(m >> 4) * 24 + (kc8 >> 2)) * 64 + (kc8 & 3) * 16 + (m & 15);
        *reinterpret_cast<short8*>(afrag + go * 8) = o;
        return;
    }
    b -= 3072;
    if (b < 864) {             // ipw (2304x768): rows<768 -> bfragQ, rows>=768 -> bfragKV
        const int u  = b * 256 + t;
        const int i8 = u * 8;
        const int row = i8 / H_, kc8 = (i8 % H_) / 8;
        const float4 v0 = *reinterpret_cast<const float4*>(ipw + i8);
        const float4 v1 = *reinterpret_cast<const float4*>(ipw + i8 + 4);
        short8 o;
        o[0]=f2b(v0.x); o[1]=f2b(v0.y); o[2]=f2b(v0.z); o[3]=f2b(v0.w);
        o[4]=f2b(v1.x); o[5]=f2b(v1.y); o[6]=f2b(v1.z); o[7]=f2b(v1.w);
        const int rr = row & 15;
        if (row < H_) {
            const long go = ((long)(row >> 4) * 24 + (kc8 >> 2)) * 64 + (kc8 & 3) * 16 + rr;
            *reinterpret_cast<short8*>(bfragQ + go * 8) = o;
        } else {
            const long go = ((long)((row - H_) >> 4) * 24 + (kc8 >> 2)) * 64 + (kc8 & 3) * 16 + rr;
            *reinterpret_cast<short8*>(bfragKV + go * 8) = o;
        }
        return;
    }
    b -= 864;
    if (b < 96) {              // lq / lw (50x768, padded to 128 rows), output-granule
        const bool isLw = (b >= 48);
        const int o = (isLw ? b - 48 : b) * 256 + t;   // granule 0..12287
        const int lane = o & 63, kt = (o >> 6) % 24, mt = o / 1536;
        const int rr = lane & 15, g = lane >> 4;
        const int m = mt * 16 + rr, c8 = kt * 4 + g;
        short8 ov;
        #pragma unroll
        for (int i = 0; i < 8; ++i) ov[i] = 0;
        if (m < NL_) {
            const float* src = (isLw ? lwt : lq) + (long)m * H_ + c8 * 8;
            const float4 v0 = *reinterpret_cast<const float4*>(src);
            const float4 v1 = *reinterpret_cast<const float4*>(src + 4);
            ov[0]=f2b(v0.x); ov[1]=f2b(v0.y); ov[2]=f2b(v0.z); ov[3]=f2b(v0.w);
            ov[4]=f2b(v1.x); ov[5]=f2b(v1.y); ov[6]=f2b(v1.z); ov[7]=f2b(v1.w);
        }
        *reinterpret_cast<short8*>((isLw ? afragLW : afragLQ) + (long)o * 8) = ov;
        return;
    }
    b -= 96;
    {                          // ow (768x768) -> bfragM2 (transposed), output-granule
        const int o = b * 256 + t;         // 0..73727
        const int lane = o & 63, kt = (o >> 6) % 24, nt = o / 1536;
        const int rr = lane & 15, g = lane >> 4;
        const int h = nt * 16 + rr, j0 = kt * 32 + g * 8;
        short8 ov;
        #pragma unroll
        for (int i = 0; i < 8; ++i) ov[i] = f2b(ow[(long)(j0 + i) * H_ + h]);
        *reinterpret_cast<short8*>(bfragM2 + (long)o * 8) = ov;
    }
}

// ---------------------------------------------------------------------------
// gemm_all: NO-LDS, NO-BARRIER MFMA GEMM on fragment-ordered inputs.
// Per wave: 4x4 frags of 16x16x32; per K-step 8 lane-linear 1KB loads + 16 MFMA.
// Explicit 3-slot register pipeline: loads issued 2 K-steps ahead.
//  by==0 : Q  (bx<6): afragLQ @ bfragQ^T + ipb -> q_b bf16 *0.125
//  by==1 : M2 (bx<6): afragLW @ bfragM2^T -> M2f f32
//  by>=2 : KV : afrag @ bfragKV^T + ipb[768+] ->
//               n<768: k_b[row][n] ; n>=768: vt_b[n-768][row]
// ---------------------------------------------------------------------------
__global__ __launch_bounds__(256)
void gemm_all(const u16* __restrict__ afrag, const u16* __restrict__ bfragKV,
              const u16* __restrict__ afragLQ, const u16* __restrict__ bfragQ,
              const u16* __restrict__ afragLW, const u16* __restrict__ bfragM2,
              const float* __restrict__ ipb,
              u16* __restrict__ k_b, u16* __restrict__ vt_b,
              u16* __restrict__ q_b, float* __restrict__ M2f)
{
    int bx = blockIdx.x, by = blockIdx.y;
    const u16 *Af, *Bf;
    const float* bias = nullptr;
    int mode, mtb, ntb;
    if (by == 0)      { if (bx >= 6) return; mode = 1; Af = afragLQ; Bf = bfragQ;  bias = ipb; mtb = 0; ntb = bx * 8; }
    else if (by == 1) { if (bx >= 6) return; mode = 2; Af = afragLW; Bf = bfragM2; mtb = 0; ntb = bx * 8; }
    else {
        mode = 0;
        const int flat = (by - 2) * 12 + bx;            // 0..767
        const int rem  = (flat & 7) * 96 + (flat >> 3); // XCD-bijective
        by = rem / 12; bx = rem % 12;
        Af = afrag; Bf = bfragKV; bias = ipb + H_;
        mtb = by * 8; ntb = bx * 8;
    }

    const int tid  = threadIdx.x;
    const int lane = tid & 63;
    const int w    = tid >> 6;
    const int wr   = w >> 1, wc = w & 1;

    // per-wave fragment base pointers (lane-linear granules of 512 elems)
    const u16* Ap = Af + (((long)(mtb + wr * 4) * 24) * 64 + lane) * 8;
    const u16* Bp = Bf + (((long)(ntb + wc * 4) * 24) * 64 + lane) * 8;

    f32x4 acc[4][4];
    #pragma unroll
    for (int m = 0; m < 4; ++m)
        #pragma unroll
        for (int n = 0; n < 4; ++n)
            #pragma unroll
            for (int j = 0; j < 4; ++j) acc[m][n][j] = 0.f;

    short8 aR[3][4], bR[3][4];

    #define LDF(s, t)                                                          \
        {                                                                      \
            _Pragma("unroll")                                                  \
            for (int m_ = 0; m_ < 4; ++m_) {                                   \
                aR[s][m_] = *reinterpret_cast<const short8*>(Ap + ((long)m_ * 24 + (t)) * 512); \
                bR[s][m_] = *reinterpret_cast<const short8*>(Bp + ((long)m_ * 24 + (t)) * 512); \
            }                                                                  \
        }

    LDF(0, 0)
    LDF(1, 1)

    #pragma unroll
    for (int t = 0; t < NT_; ++t) {
        const int cs = t % 3;
        if (t + 2 < NT_) {
            const int ns = (t + 2) % 3;
            LDF(ns, t + 2)
        }
        #pragma unroll
        for (int m = 0; m < 4; ++m)
            #pragma unroll
            for (int n = 0; n < 4; ++n)
                acc[m][n] = __builtin_amdgcn_mfma_f32_16x16x32_bf16(
                    aR[cs][m], bR[cs][n], acc[m][n], 0, 0, 0);
    }
    #undef LDF

    // epilogue: C/D layout col=lane&15, row=(lane>>4)*4+j
    const long m0 = (long)mtb * 16, n0 = (long)ntb * 16;
    const int col16 = lane & 15, row4 = (lane >> 4) * 4;
    #pragma unroll
    for (int m = 0; m < 4; ++m) {
        #pragma unroll
        for (int n = 0; n < 4; ++n) {
            const long col = n0 + wc * 64 + n * 16 + col16;
            const float bv = bias ? bias[col] : 0.f;
            #pragma unroll
            for (int j = 0; j < 4; ++j) {
                const long row = m0 + wr * 64 + m * 16 + row4 + j;
                const float v = acc[m][n][j] + bv;
                if (mode == 0) {
                    if (col < H_) k_b[row * H_ + col] = f2b(v);
                    else          vt_b[(col - H_) * (long)S_ + row] = f2b(v);
                } else if (mode == 1) {
                    q_b[row * H_ + col] = f2b(v * 0.125f);
                } else {
                    M2f[row * H_ + col] = v;
                }
            }
        }
    }
}

// ---------------------------------------------------------------------------
// attn: block = (h, cc). 256 threads. 256-key subchunk partials, all 50 labels.
//  - K frags loaded DIRECTLY global->registers (zero reuse, skip LDS)
//  - V^T staged async via global_load_lds (swizzled source), consumed by PV
//  - P transposed through LDS (XOR slot swizzle)
// ---------------------------------------------------------------------------
__global__ __launch_bounds__(256, 1)
void attn(const u16* __restrict__ q_b, const u16* __restrict__ k_b,
          const u16* __restrict__ vt_b,
          float* __restrict__ pm, float* __restrict__ pp, float* __restrict__ pctx)
{
    const int h  = blockIdx.x;   // 0..11
    const int cc = blockIdx.y;   // 0..31
    const int tid = threadIdx.x;
    const int lane = tid & 63;
    const int w    = tid >> 6;
    const int g    = lane >> 4;
    const int l15  = lane & 15;

    __shared__ u16 P[64 * 256];    // 32 KB
    __shared__ u16 Vb[64 * 256];   // 32 KB
    __shared__ float red[576];

    // --- issue V^T stage (64 d x 256 s), pre-swizzled source ---
    const long vbase = (long)h * DH_ * S_ + (long)cc * SC_;
    #pragma unroll
    for (int p = 0; p < 8; ++p) {
        const int d  = p * 8 + (tid >> 5);
        const int sc = (tid & 31) ^ (d & 15);
        __builtin_amdgcn_global_load_lds(AS1(vt_b + vbase + (long)d * S_ + sc * 8),
                                         AS3(Vb + p * 2048 + tid * 8), 16, 0, 0);
    }

    // --- Q fragments ---
    short8 aq[4][2];
    #pragma unroll
    for (int lt = 0; lt < 4; ++lt)
        #pragma unroll
        for (int ks = 0; ks < 2; ++ks)
            aq[lt][ks] = *reinterpret_cast<const short8*>(
                q_b + (long)(lt * 16 + l15) * H_ + h * DH_ + ks * 32 + g * 8);

    // --- K fragments direct from global ---
    const long kbase = (long)cc * SC_ * H_ + h * DH_;
    short8 bk[4][2];
    #pragma unroll
    for (int st = 0; st < 4; ++st)
        #pragma unroll
        for (int ks = 0; ks < 2; ++ks)
            bk[st][ks] = *reinterpret_cast<const short8*>(
                k_b + kbase + (long)(w * 64 + st * 16 + l15) * H_ + ks * 32 + g * 8);

    // --- QK^T ---
    f32x4 acc[4][4];
    #pragma unroll
    for (int lt = 0; lt < 4; ++lt)
        #pragma unroll
        for (int st = 0; st < 4; ++st)
            #pragma unroll
            for (int j = 0; j < 4; ++j) acc[lt][st][j] = 0.f;
    #pragma unroll
    for (int ks = 0; ks < 2; ++ks)
        #pragma unroll
        for (int lt = 0; lt < 4; ++lt)
            #pragma unroll
            for (int st = 0; st < 4; ++st)
                acc[lt][st] = __builtin_amdgcn_mfma_f32_16x16x32_bf16(
                    aq[lt][ks], bk[st][ks], acc[lt][st], 0, 0, 0);

    // --- wave-local max + block max ---
    #pragma unroll
    for (int lt = 0; lt < 4; ++lt)
        #pragma unroll
        for (int j = 0; j < 4; ++j) {
            float m = fmaxf(fmaxf(acc[lt][0][j], acc[lt][1][j]),
                            fmaxf(acc[lt][2][j], acc[lt][3][j]));
            #pragma unroll
            for (int o = 1; o < 16; o <<= 1) m = fmaxf(m, __shfl_xor(m, o));
            if (l15 == 0) red[w * 64 + lt * 16 + g * 4 + j] = m;
        }
    __syncthreads();   // [B1]
    if (tid < 64)
        red[512 + tid] = fmaxf(fmaxf(red[tid], red[64 + tid]),
                               fmaxf(red[128 + tid], red[192 + tid]));
    __syncthreads();   // [B2]

    // --- exp + P write (swizzled) + sum ---
    float mg[4][4];
    #pragma unroll
    for (int lt = 0; lt < 4; ++lt)
        #pragma unroll
        for (int j = 0; j < 4; ++j) mg[lt][j] = red[512 + lt * 16 + g * 4 + j];
    #pragma unroll
    for (int lt = 0; lt < 4; ++lt)
        #pragma unroll
        for (int st = 0; st < 4; ++st)
            #pragma unroll
            for (int j = 0; j < 4; ++j)
                acc[lt][st][j] = __expf(acc[lt][st][j] - mg[lt][j]);
    #pragma unroll
    for (int lt = 0; lt < 4; ++lt)
        #pragma unroll
        for (int st = 0; st < 4; ++st)
            #pragma unroll
            for (int j = 0; j < 4; ++j) {
                const int l  = lt * 16 + g * 4 + j;
                const int sl = w * 64 + st * 16 + l15;
                const int byte = l * 512 + ((sl * 2) ^ ((l & 15) << 4));
                *(u16*)((char*)P + byte) = f2b(acc[lt][st][j]);
            }
    #pragma unroll
    for (int lt = 0; lt < 4; ++lt)
        #pragma unroll
        for (int j = 0; j < 4; ++j) {
            float s = acc[lt][0][j] + acc[lt][1][j] + acc[lt][2][j] + acc[lt][3][j];
            #pragma unroll
            for (int o = 1; o < 16; o <<= 1) s += __shfl_xor(s, o);
            if (l15 == 0) red[256 + w * 64 + lt * 16 + g * 4 + j] = s;
        }
    __syncthreads();   // [B3]

    if (tid < NL_) {
        const long idx = ((long)cc * NH_ + h) * NL_ + tid;
        pm[idx] = red[512 + tid];
        pp[idx] = red[256 + tid] + red[320 + tid] + red[384 + tid] + red[448 + tid];
    }

    // --- PV: wave w owns labels [w*16, w*16+16) ---
    f32x4 acc2[4];
    #pragma unroll
    for (int dt = 0; dt < 4; ++dt)
        #pragma unroll
        for (int j = 0; j < 4; ++j) acc2[dt][j] = 0.f;

    const int lrow = w * 16 + l15;
    const int lx   = l15 << 4;
    #pragma unroll
    for (int ks = 0; ks < 8; ++ks) {
        const int ch = ks * 4 + g;
        const short8 pa = *reinterpret_cast<const short8*>(
            (const char*)P + lrow * 512 + ((ch << 4) ^ lx));
        #pragma unroll
        for (int dt = 0; dt < 4; ++dt) {
            const int dl = dt * 16 + l15;
            const short8 vb = *reinterpret_cast<const short8*>(
                (const char*)Vb + dl * 512 + ((ch ^ l15) << 4));
            acc2[dt] = __builtin_amdgcn_mfma_f32_16x16x32_bf16(pa, vb, acc2[dt], 0, 0, 0);
        }
    }

    #pragma unroll
    for (int dt = 0; dt < 4; ++dt)
        #pragma unroll
        for (int j = 0; j < 4; ++j) {
            const int l = w * 16 + g * 4 + j;
            if (l < NL_) {
                const long idx = ((long)cc * NH_ + h) * NL_ + l;
                pctx[idx * DH_ + dt * 16 + l15] = acc2[dt][j];
            }
        }
}

// ---------------------------------------------------------------------------
// combine_score: block = label l. Prefix-combine 32 subchunk partials; emit
// score at every 2nd subchunk (chunk boundary).
// ---------------------------------------------------------------------------
__global__ __launch_bounds__(256)
void combine_score(const float* __restrict__ pm, const float* __restrict__ pp,
                   const float* __restrict__ pctx, const float* __restrict__ M2f,
                   const float* __restrict__ lw, const float* __restrict__ ob,
                   float* __restrict__ out)
{
    const int l = blockIdx.x;
    const int tid = threadIdx.x;
    const int w = tid >> 6, lane = tid & 63;
    __shared__ float wred[4], bred[4];

    float bp = 0.f;
    #pragma unroll
    for (int r = 0; r < 3; ++r) {
        const int i = tid + 256 * r;
        bp += lw[(long)l * H_ + i] * ob[i];
    }
    #pragma unroll
    for (int o = 1; o < 64; o <<= 1) bp += __shfl_xor(bp, o);
    if (lane == 0) bred[w] = bp;

    float M[3], Ssum[3], A[3];
    #pragma unroll
    for (int r = 0; r < 3; ++r) { M[r] = -INFINITY; Ssum[r] = 0.f; A[r] = 0.f; }

    for (int cc = 0; cc < NCH_; ++cc) {
        #pragma unroll
        for (int r = 0; r < 3; ++r) {
            const int i = tid + 256 * r;
            const int hh = i >> 6, d = i & 63;
            const long idx = ((long)cc * NH_ + hh) * NL_ + l;
            const float mc = pm[idx], pc = pp[idx];
            const float Mn = fmaxf(M[r], mc);
            const float ea = __expf(M[r] - Mn), eb = __expf(mc - Mn);
            Ssum[r] = Ssum[r] * ea + pc * eb;
            A[r]    = A[r] * ea + pctx[idx * DH_ + d] * eb;
            M[r] = Mn;
        }
        if (cc & 1) {
            float t = 0.f;
            #pragma unroll
            for (int r = 0; r < 3; ++r) {
                const int i = tid + 256 * r;
                t += (A[r] / Ssum[r]) * M2f[(long)l * H_ + i];
            }
            #pragma unroll
            for (int o = 1; o < 64; o <<= 1) t += __shfl_xor(t, o);
            if (lane == 0) wred[w] = t;
            __syncthreads();
            if (tid == 0)
                out[(long)(cc >> 1) * NL_ + l] = wred[0] + wred[1] + wred[2] + wred[3]
                                               + bred[0] + bred[1] + bred[2] + bred[3];
            __syncthreads();
        }
    }
}

// ---------------------------------------------------------------------------
extern "C" void kernel_launch(void* const* d_in, const int* in_sizes, int n_in,
                              void* d_out, int out_size, void* d_ws, size_t ws_size,
                              hipStream_t stream) {
    const float* enc = (const float*)d_in[0];
    const float* lq  = (const float*)d_in[1];
    const float* lwt = (const float*)d_in[2];
    const float* ipw = (const float*)d_in[3];
    const float* ipb = (const float*)d_in[4];
    const float* ow  = (const float*)d_in[5];
    const float* ob  = (const float*)d_in[6];
    float* out = (float*)d_out;

    // workspace: f32 region then bf16 region (16B aligned throughout)
    float* wsf  = (float*)d_ws;
    float* pctx = wsf;                                    // 32*12*50*64 = 1228800
    float* M2f  = pctx + (long)NCH_ * NH_ * NL_ * DH_;    // 128*768
    float* pm   = M2f + (long)128 * H_;                   // 19200
    float* pp   = pm + (long)NCH_ * NH_ * NL_;            // 19200
    u16* afrag   = (u16*)(pp + (long)NCH_ * NH_ * NL_);   // 8192*768
    u16* bfragKV = afrag + (long)S_ * H_;                 // 1536*768
    u16* bfragQ  = bfragKV + (long)2 * H_ * H_;           // 768*768
    u16* afragLQ = bfragQ + (long)H_ * H_;                // 128*768
    u16* afragLW = afragLQ + (long)128 * H_;              // 128*768
    u16* bfragM2 = afragLW + (long)128 * H_;              // 768*768
    u16* q_b  = bfragM2 + (long)H_ * H_;                  // 128*768
    u16* k_b  = q_b + (long)128 * H_;                     // 8192*768
    u16* vt_b = k_b + (long)S_ * H_;                      // 768*8192

    prep_all<<<dim3(3072 + 864 + 96 + 288), 256, 0, stream>>>(
        enc, ipw, lq, lwt, ow, afrag, bfragKV, bfragQ, afragLQ, afragLW, bfragM2);

    gemm_all<<<dim3(12, 66), 256, 0, stream>>>(
        afrag, bfragKV, afragLQ, bfragQ, afragLW, bfragM2, ipb, k_b, vt_b, q_b, M2f);

    attn<<<dim3(NH_, NCH_), 256, 0, stream>>>(q_b, k_b, vt_b, pm, pp, pctx);

    combine_score<<<dim3(NL_), 256, 0, stream>>>(pm, pp, pctx, M2f, lwt, ob, out);
}